// Round 11
// baseline (64.448 us; speedup 1.0000x reference)
//
#include <hip/hip_runtime.h>
#include <math.h>

#define VOCAB 4096
#define NROWS 65536          // B*L = 4*16384
#define DECAYF 0.99f
#define EPSF 1e-5f

typedef unsigned long long u64;
typedef unsigned int u32;
typedef float vf2 __attribute__((ext_vector_type(2)));

// ---------------- ws layout (bytes) ----------------
// [0,    2048)  errpart: 256 doubles
// [2048, 2052)  n value (float), written by seg's extra block
// [4096, 4096 + NSEG*VOCAB*16)  part[NSEG][VOCAB] float4 (cnt,w0,w1,w2)

// Scan: block=1024 (16 waves), grid=256. 64KB LDS pair-transposed table.
// Lane owns 4 rows; wave scans 256 cands as 32 groups of 8 with an explicit
// REGISTER DOUBLE-BUFFER: group g+1's 8 ds_read_b128 issue before group g's
// math, so LDS latency hides under VALU. One strict-< select per group; exact
// index recovered afterwards by bit-identical recompute of the winning group.
__global__ __launch_bounds__(1024, 4) void vq_scan_kernel(
    const float* __restrict__ feats,
    const float* __restrict__ embed,
    float* __restrict__ quant_out,
    float* __restrict__ idx_out,
    double* __restrict__ errpart) {
    #pragma clang fp contract(off)
    __shared__ float4 tab[VOCAB];          // 64 KB; aliased as merge scratch later

    const int tid  = threadIdx.x;
    const int wave = tid >> 6;
    const int lane = tid & 63;

    // stage pair-transposed packed table (thread handles pairs t, t+1024)
    #pragma unroll
    for (int k = 0; k < 2; ++k) {
        const int p = tid + k * 1024;      // pair id 0..2047
        const float* e = embed + p * 6;
        const float x0 = e[0], y0 = e[1], z0 = e[2];
        const float x1 = e[3], y1 = e[4], z1 = e[5];
        // numpy rounding: (x^2 + y^2) + z^2, each product rounded
        const float s0 = (x0 * x0 + y0 * y0) + z0 * z0;
        const float s1 = (x1 * x1 + y1 * y1) + z1 * z1;
        tab[2 * p]     = make_float4(-2.f * x0, -2.f * x1, -2.f * y0, -2.f * y1);
        tab[2 * p + 1] = make_float4(-2.f * z0, -2.f * z1, s0, s1);
    }

    // lane's 4 rows: 48 B contiguous = 3x float4
    const int rbase = blockIdx.x * 256 + lane * 4;
    const float4 fa = *(const float4*)(feats + rbase * 3);
    const float4 fb = *(const float4*)(feats + rbase * 3 + 4);
    const float4 fc = *(const float4*)(feats + rbase * 3 + 8);
    const float f0[4] = {fa.x, fa.w, fb.z, fc.y};
    const float f1[4] = {fa.y, fb.x, fb.w, fc.z};
    const float f2[4] = {fa.z, fb.y, fc.x, fc.w};
    vf2 f0s[4], f1s[4], f2s[4], fss[4];    // loop-invariant splats
    #pragma unroll
    for (int r = 0; r < 4; ++r) {
        const float fs = (f0[r] * f0[r] + f1[r] * f1[r]) + f2[r] * f2[r];
        f0s[r] = (vf2){f0[r], f0[r]};
        f1s[r] = (vf2){f1[r], f1[r]};
        f2s[r] = (vf2){f2[r], f2[r]};
        fss[r] = (vf2){fs, fs};
    }

    __syncthreads();

    float best[4] = {INFINITY, INFINITY, INFINITY, INFINITY};
    int   gb[4]   = {0, 0, 0, 0};          // winning group base (global cand idx)
    const float4* __restrict__ wt = tab + (wave << 8);   // 256 float4 = 256 cands
    const int cw = wave << 8;

    // register double-buffer: A* = current group, N* = next group
    float4 A0 = wt[0], B0 = wt[1], A1 = wt[2], B1 = wt[3];
    float4 A2 = wt[4], B2 = wt[5], A3 = wt[6], B3 = wt[7];

    for (int g = 0; g < 32; ++g) {
        const int nb = ((g + 1) & 31) << 3;        // wrap keeps loads uniform
        const float4 N0 = wt[nb + 0], M0 = wt[nb + 1];
        const float4 N1 = wt[nb + 2], M1 = wt[nb + 3];
        const float4 N2 = wt[nb + 4], M2 = wt[nb + 5];
        const float4 N3 = wt[nb + 6], M3 = wt[nb + 7];

        const vf2 xs0 = {A0.x, A0.y}, ys0 = {A0.z, A0.w}, zs0 = {B0.x, B0.y}, es0 = {B0.z, B0.w};
        const vf2 xs1 = {A1.x, A1.y}, ys1 = {A1.z, A1.w}, zs1 = {B1.x, B1.y}, es1 = {B1.z, B1.w};
        const vf2 xs2 = {A2.x, A2.y}, ys2 = {A2.z, A2.w}, zs2 = {B2.x, B2.y}, es2 = {B2.z, B2.w};
        const vf2 xs3 = {A3.x, A3.y}, ys3 = {A3.z, A3.w}, zs3 = {B3.x, B3.y}, es3 = {B3.z, B3.w};
        const int cbase = cw + (g << 3);
        #pragma unroll
        for (int r = 0; r < 4; ++r) {
            // per half: fmaf(z',f2,fmaf(y',f1,x'*f0)); (fs+t)+s  (ref-exact)
            vf2 t0 = __builtin_elementwise_fma(zs0, f2s[r], __builtin_elementwise_fma(ys0, f1s[r], xs0 * f0s[r]));
            vf2 t1 = __builtin_elementwise_fma(zs1, f2s[r], __builtin_elementwise_fma(ys1, f1s[r], xs1 * f0s[r]));
            vf2 t2 = __builtin_elementwise_fma(zs2, f2s[r], __builtin_elementwise_fma(ys2, f1s[r], xs2 * f0s[r]));
            vf2 t3 = __builtin_elementwise_fma(zs3, f2s[r], __builtin_elementwise_fma(ys3, f1s[r], xs3 * f0s[r]));
            vf2 d0 = (fss[r] + t0) + es0;
            vf2 d1 = (fss[r] + t1) + es1;
            vf2 d2 = (fss[r] + t2) + es2;
            vf2 d3 = (fss[r] + t3) + es3;
            vf2 m01 = __builtin_elementwise_min(d0, d1);
            vf2 m23 = __builtin_elementwise_min(d2, d3);
            vf2 m   = __builtin_elementwise_min(m01, m23);
            const float m8 = fminf(m.x, m.y);
            if (m8 < best[r]) { best[r] = m8; gb[r] = cbase; }   // strict <
        }
        A0 = N0; B0 = M0; A1 = N1; B1 = M1;
        A2 = N2; B2 = M2; A3 = N3; B3 = M3;
    }

    // ---- recovery: exact first index inside each row's winning group ----
    u64 key[4];
    #pragma unroll
    for (int r = 0; r < 4; ++r) {
        const int b0 = gb[r];              // global cand base (also tab index)
        const float bv = best[r];
        int idx = b0;
        #pragma unroll
        for (int k = 3; k >= 0; --k) {     // descending -> lowest index wins
            const float4 A = tab[b0 + 2 * k];
            const float4 B = tab[b0 + 2 * k + 1];
            const vf2 xs = {A.x, A.y}, ys = {A.z, A.w}, zs = {B.x, B.y}, es = {B.z, B.w};
            vf2 t = __builtin_elementwise_fma(zs, f2s[r], __builtin_elementwise_fma(ys, f1s[r], xs * f0s[r]));
            vf2 d = (fss[r] + t) + es;     // bit-identical to scan path
            if (d.y == bv) idx = b0 + 2 * k + 1;
            if (d.x == bv) idx = b0 + 2 * k;
        }
        const u32 bb = __float_as_uint(bv);
        const u32 mb = bb ^ ((u32)((int)bb >> 31) | 0x80000000u);   // total order
        key[r] = ((u64)mb << 32) | (u32)idx;
    }

    __syncthreads();                       // all waves done reading tab
    u64* mk = (u64*)tab;                   // [16][4][64] = 32 KB, aliases tab
    if (wave != 0) {
        #pragma unroll
        for (int r = 0; r < 4; ++r)
            mk[(wave * 4 + r) * 64 + lane] = key[r];
    }
    __syncthreads();
    if (wave == 0) {
        for (int w = 1; w < 16; ++w) {
            #pragma unroll
            for (int r = 0; r < 4; ++r) {
                const u64 k = mk[(w * 4 + r) * 64 + lane];
                key[r] = k < key[r] ? k : key[r];
            }
        }
        int cand[4];
        #pragma unroll
        for (int r = 0; r < 4; ++r) cand[r] = (int)(u32)key[r];

        *(float4*)(idx_out + rbase) =
            make_float4((float)cand[0], (float)cand[1], (float)cand[2], (float)cand[3]);

        float q[4][3];
        #pragma unroll
        for (int r = 0; r < 4; ++r) {
            q[r][0] = embed[cand[r] * 3 + 0];
            q[r][1] = embed[cand[r] * 3 + 1];
            q[r][2] = embed[cand[r] * 3 + 2];
        }
        *(float4*)(quant_out + rbase * 3)     = make_float4(q[0][0], q[0][1], q[0][2], q[1][0]);
        *(float4*)(quant_out + rbase * 3 + 4) = make_float4(q[1][1], q[1][2], q[2][0], q[2][1]);
        *(float4*)(quant_out + rbase * 3 + 8) = make_float4(q[2][2], q[3][0], q[3][1], q[3][2]);

        float err = 0.0f;
        #pragma unroll
        for (int r = 0; r < 4; ++r) {
            const float d0 = q[r][0] - f0[r], d1 = q[r][1] - f1[r], d2 = q[r][2] - f2[r];
            err += d0 * d0 + d1 * d1 + d2 * d2;
        }
        #pragma unroll
        for (int off = 32; off >= 1; off >>= 1) err += __shfl_xor(err, off);
        if (lane == 0) errpart[blockIdx.x] = (double)err;
    }
}

// Segment sums, LDS-privatized; blocks [0,nseg) accumulate partials; the extra
// block (== nseg) computes n = DECAY*sum(ema_cs) + (1-DECAY)*NROWS.
__global__ __launch_bounds__(1024) void seg_kernel(
    const float* __restrict__ feats,
    const float* __restrict__ idx_f,
    const float* __restrict__ ema_cs,
    float4* __restrict__ part,
    float* __restrict__ n_out,
    int iters, int nseg) {
    __shared__ float lcnt[VOCAB];          // 16 KB
    __shared__ float lw[VOCAB * 3];        // 48 KB
    const int t = threadIdx.x;
    const int b = blockIdx.x;

    if (b == nseg) {                       // n block (input-only reduction)
        float s = ema_cs[t] + ema_cs[t + 1024] + ema_cs[t + 2048] + ema_cs[t + 3072];
        #pragma unroll
        for (int off = 32; off >= 1; off >>= 1) s += __shfl_xor(s, off);
        if ((t & 63) == 0) lcnt[t >> 6] = s;
        __syncthreads();
        if (t == 0) {
            float S = 0.f;
            #pragma unroll
            for (int w = 0; w < 16; ++w) S += lcnt[w];
            *n_out = DECAYF * S + (1.0f - DECAYF) * (float)NROWS;
        }
        return;
    }

    #pragma unroll
    for (int i = 0; i < 4; ++i)  lcnt[t + i * 1024] = 0.0f;
    #pragma unroll
    for (int i = 0; i < 12; ++i) lw[t + i * 1024] = 0.0f;
    __syncthreads();

    const int base = b * iters * 1024;
    for (int i = 0; i < iters; ++i) {
        const int row = base + i * 1024 + t;
        const int cand = (int)idx_f[row];
        atomicAdd(&lcnt[cand], 1.0f);
        atomicAdd(&lw[cand * 3 + 0], feats[row * 3 + 0]);
        atomicAdd(&lw[cand * 3 + 1], feats[row * 3 + 1]);
        atomicAdd(&lw[cand * 3 + 2], feats[row * 3 + 2]);
    }
    __syncthreads();

    #pragma unroll
    for (int i = 0; i < 4; ++i) {
        const int v = t + i * 1024;
        part[b * VOCAB + v] = make_float4(lcnt[v], lw[3 * v], lw[3 * v + 1], lw[3 * v + 2]);
    }
}

// Reduce partials (ascending b = row-ascending order) + EMA + normalize + loss.
__global__ __launch_bounds__(256) void ema_final_kernel(
    const float4* __restrict__ part,
    const float* __restrict__ ema_cs,
    const float* __restrict__ ema_w,
    const double* __restrict__ errpart,
    const float* __restrict__ n_out,
    float* __restrict__ ncs_out,
    float* __restrict__ nw_out,
    float* __restrict__ embed_out,
    float* __restrict__ loss_out,
    int nseg) {
    const int v = blockIdx.x * 256 + threadIdx.x;
    float c = 0.f, w0 = 0.f, w1 = 0.f, w2 = 0.f;
    for (int b = 0; b < nseg; ++b) {
        const float4 p = part[b * VOCAB + v];
        c += p.x; w0 += p.y; w1 += p.z; w2 += p.w;
    }
    const float ncs = DECAYF * ema_cs[v] + (1.0f - DECAYF) * c;
    const float n0  = DECAYF * ema_w[v * 3 + 0] + (1.0f - DECAYF) * w0;
    const float n1  = DECAYF * ema_w[v * 3 + 1] + (1.0f - DECAYF) * w1;
    const float n2  = DECAYF * ema_w[v * 3 + 2] + (1.0f - DECAYF) * w2;
    ncs_out[v] = ncs;
    nw_out[v * 3 + 0] = n0;
    nw_out[v * 3 + 1] = n1;
    nw_out[v * 3 + 2] = n2;

    const float n = *n_out;
    const float cs = (ncs + EPSF) / (n + (float)VOCAB * EPSF) * n;
    const float d0 = n0 / cs;
    const float d1 = n1 / cs;
    const float d2 = n2 / cs;
    const float nrm = fmaxf(sqrtf(d1 * d1 + d2 * d2), EPSF);
    embed_out[v * 3 + 0] = d0;
    embed_out[v * 3 + 1] = d1 / nrm;
    embed_out[v * 3 + 2] = d2 / nrm;

    if (blockIdx.x == 0) {                 // loss from the 256 scan partials
        __shared__ double se[256];
        const int t = threadIdx.x;
        se[t] = errpart[t];
        __syncthreads();
        #pragma unroll
        for (int s = 128; s > 0; s >>= 1) {
            if (t < s) se[t] += se[t + s];
            __syncthreads();
        }
        if (t == 0)
            loss_out[0] = (float)(1.25 * se[0] / (double)(NROWS * 3));
    }
}

extern "C" void kernel_launch(void* const* d_in, const int* in_sizes, int n_in,
                              void* d_out, int out_size, void* d_ws, size_t ws_size,
                              hipStream_t stream) {
    const float* feats  = (const float*)d_in[0];   // 65536*3
    const float* embed  = (const float*)d_in[1];   // 4096*3
    const float* ema_cs = (const float*)d_in[2];   // 4096
    const float* ema_w  = (const float*)d_in[3];   // 4096*3

    float* out = (float*)d_out;
    float* quant_out = out;                         // 196608
    float* idx_out   = out + 196608;                // 65536
    float* loss_out  = out + 262144;                // 1
    float* embed_out = out + 262145;                // 12288
    float* ncs_out   = out + 274433;                // 4096
    float* nw_out    = out + 278529;                // 12288

    char* wsb = (char*)d_ws;
    double* errpart = (double*)wsb;                 // 256 doubles
    float*  n_out   = (float*)(wsb + 2048);         // 1 float
    float4* part    = (float4*)(wsb + 4096);        // NSEG*4096 float4

    // NSEG from ws_size (deterministic; 8 proven safe at ~516 KB)
    const size_t per_seg = (size_t)VOCAB * 16;
    const size_t avail = ws_size > 4096 ? ws_size - 4096 : 0;
    int nseg = 8;
    if (avail >= 64 * per_seg)      nseg = 64;
    else if (avail >= 32 * per_seg) nseg = 32;
    else if (avail >= 16 * per_seg) nseg = 16;
    const int iters = NROWS / (nseg * 1024);

    vq_scan_kernel<<<NROWS / 256, 1024, 0, stream>>>(feats, embed,
                                                     quant_out, idx_out, errpart);
    seg_kernel<<<nseg + 1, 1024, 0, stream>>>(feats, idx_out, ema_cs,
                                              part, n_out, iters, nseg);
    ema_final_kernel<<<VOCAB / 256, 256, 0, stream>>>(part, ema_cs, ema_w,
                                                      errpart, n_out,
                                                      ncs_out, nw_out, embed_out,
                                                      loss_out, nseg);
}